// Round 24
// baseline (159.065 us; speedup 1.0000x reference)
//
#include <hip/hip_runtime.h>
#include <hip/hip_bf16.h>

#define B_ 4
#define N_ 10000
#define E_ 160000
#define D_ 128
#define H_ 4
#define HID_ 128
#define DK_ 32
#define DE_ 16
#define PGRID 2048
#define QKV_BLKS 625
#define FILM_BLKS 1024
#define HIST_BLKS 625   // ceil(E/256)

typedef __attribute__((ext_vector_type(8))) short short8v;
typedef __attribute__((ext_vector_type(4))) short short4v;
typedef __attribute__((ext_vector_type(4))) float f32x4;
typedef __attribute__((ext_vector_type(2))) float f32x2;

// fp32 -> bf16 bits, round-to-nearest-even
__device__ __forceinline__ short bfb(float f) {
  union { float f; unsigned u; } c; c.f = f;
  unsigned u = c.u + 0x7FFFu + ((c.u >> 16) & 1u);
  return (short)(u >> 16);
}
// bf16 bits -> fp32
__device__ __forceinline__ float b2f(unsigned short u) {
  union { unsigned u; float f; } c; c.u = ((unsigned)u) << 16;
  return c.f;
}
// dword of 4 fp8 -> 2+2 fp32
__device__ __forceinline__ f32x2 fp8lo(unsigned u) {
  return __builtin_amdgcn_cvt_pk_f32_fp8((int)u, false);
}
__device__ __forceinline__ f32x2 fp8hi(unsigned u) {
  return __builtin_amdgcn_cvt_pk_f32_fp8((int)u, true);
}
// pack 4 fp32 -> dword of 4 fp8 e4m3
__device__ __forceinline__ int pk4fp8(float a, float b, float c, float d) {
  int r = __builtin_amdgcn_cvt_pk_fp8_f32(a, b, 0, false);
  r = __builtin_amdgcn_cvt_pk_fp8_f32(c, d, r, true);
  return r;
}

// ---------------------------------------------------------------------------
// P0: W^T bf16 prep + Wf^T bf16 (K padded to 32 with zeros).
// blocks [0,256): wt[m][n][k] = bf16(W_m[k*128+n]),  m: 0=q 1=k 2=v 3=o
// blocks [256,288): wfb[col][k] = k<16 ? bf16(Wf[k*256+col]) : 0
// ---------------------------------------------------------------------------
__global__ __launch_bounds__(256) void wt_prep(
    const float* __restrict__ Wq, const float* __restrict__ Wk,
    const float* __restrict__ Wv, const float* __restrict__ Wo,
    const float* __restrict__ Wf,
    short* __restrict__ wt, short* __restrict__ wfb) {
  const int blk = blockIdx.x;
  if (blk < 256) {
    const float* Ws[4] = {Wq, Wk, Wv, Wo};
    const int i = blk * 256 + threadIdx.x;   // 0..65535
    const int m = i >> 14;
    const int k = (i >> 7) & 127;
    const int n = i & 127;
    wt[(size_t)m * 16384 + n * 128 + k] = bfb(Ws[m][k * 128 + n]);
  } else {
    const int i = (blk - 256) * 256 + threadIdx.x;  // 0..8191
    const int col = i >> 5;
    const int k = i & 31;
    wfb[col * 32 + k] = (k < DE_) ? bfb(Wf[k * 256 + col]) : (short)0;
  }
}

// ---------------------------------------------------------------------------
// PHASE 1: co-scheduled qkv(MFMA) + film(MFMA) + hist.
// All MFMA out-cols remapped so one lane's cb-values are CONSECUTIVE ->
// packed 16B/8B stores instead of byte stores (6-8x fewer store insts).
// qkv: out_col = ln15*8+cb (8 MFMA, 128 cols). film: out_col = ln15*16+cb
// (16 MFMA, 256 cols), K=16 padded to 32 (A-frag zero for g>=2).
// ---------------------------------------------------------------------------
__global__ __launch_bounds__(256) void phase1(
    const float* __restrict__ x, const short* __restrict__ wt,
    const float* __restrict__ bq, const float* __restrict__ bk,
    const float* __restrict__ bv,
    unsigned short* __restrict__ Qb, unsigned char* __restrict__ kv8,
    const float* __restrict__ ea, const short* __restrict__ wfb,
    const float* __restrict__ bf, unsigned char* __restrict__ film8,
    const int* __restrict__ ei, int* __restrict__ cnt) {
  const int blk = blockIdx.x;

  if (blk < QKV_BLKS) {
    // ---------------- QKV (4 wave-tiles per block) ----------------
    __shared__ short xs[4][16][136];
    const int wave = threadIdx.x >> 6;
    const int lane = threadIdx.x & 63;
    const int ln15 = lane & 15;
    const int g    = lane >> 4;
    const long rowBase = ((long)blk * 4 + wave) * 16;

    for (int i = lane; i < 16 * 32; i += 64) {
      const int r  = i >> 5;
      const int c4 = (i & 31) * 4;
      const float4 v = *(const float4*)(x + (rowBase + r) * 128 + c4);
      short4v sv; sv.x = bfb(v.x); sv.y = bfb(v.y); sv.z = bfb(v.z); sv.w = bfb(v.w);
      *(short4v*)&xs[wave][r][c4] = sv;
    }
    __syncthreads();   // branch uniform per block -> safe

    short8v af[4];
#pragma unroll
    for (int kk = 0; kk < 4; ++kk)
      af[kk] = *(const short8v*)&xs[wave][ln15][kk * 32 + g * 8];

    const float* bs[3] = {bq, bk, bv};

    int bbv4[4], nnv[4];
#pragma unroll
    for (int r = 0; r < 4; ++r) {
      const long row = rowBase + g * 4 + r;
      bbv4[r] = (int)(row / N_);
      nnv[r] = (int)(row - (long)bbv4[r] * N_);
    }

#pragma unroll
    for (int m = 0; m < 3; ++m) {
      const short* Wt = wt + (size_t)m * 16384;
      f32x4 acc[8];
#pragma unroll
      for (int cb = 0; cb < 8; ++cb) acc[cb] = (f32x4){0.f, 0.f, 0.f, 0.f};

#pragma unroll
      for (int kk = 0; kk < 4; ++kk) {
#pragma unroll
        for (int cb = 0; cb < 8; ++cb) {
          // out_col = ln15*8 + cb  -> B row remapped
          const short8v bfr =
              *(const short8v*)(Wt + (ln15 * 8 + cb) * 128 + kk * 32 + g * 8);
          acc[cb] = __builtin_amdgcn_mfma_f32_16x16x32_bf16(af[kk], bfr, acc[cb], 0, 0, 0);
        }
      }

      const float* bias = bs[m];
      float bvv[8];
#pragma unroll
      for (int cb = 0; cb < 8; ++cb) bvv[cb] = bias[ln15 * 8 + cb];

#pragma unroll
      for (int r = 0; r < 4; ++r) {
        if (m == 0) {
          const long row = rowBase + g * 4 + r;
          short8v qs;
#pragma unroll
          for (int cb = 0; cb < 8; ++cb) qs[cb] = bfb(acc[cb][r] + bvv[cb]);
          *(short8v*)(Qb + row * 128 + ln15 * 8) = qs;
        } else {
          const int d0 = pk4fp8(acc[0][r] + bvv[0], acc[1][r] + bvv[1],
                                acc[2][r] + bvv[2], acc[3][r] + bvv[3]);
          const int d1 = pk4fp8(acc[4][r] + bvv[4], acc[5][r] + bvv[5],
                                acc[6][r] + bvv[6], acc[7][r] + bvv[7]);
          uint2 st; st.x = (unsigned)d0; st.y = (unsigned)d1;
          *(uint2*)(kv8 + (((size_t)nnv[r] * 4 + bbv4[r]) << 8) + (m - 1) * 128 +
                    ln15 * 8) = st;
        }
      }
    }
  } else if (blk < QKV_BLKS + FILM_BLKS) {
    // ---------------- FiLM via MFMA (16-edge x 256-col tiles) ----------------
    const int fb_  = blk - QKV_BLKS;
    const int wave = threadIdx.x >> 6;
    const int lane = threadIdx.x & 63;
    const int ln15 = lane & 15;
    const int g    = lane >> 4;

    // persist B frags (out_col = ln15*16 + cb) and bias
    short8v wf[16];
#pragma unroll
    for (int cb = 0; cb < 16; ++cb)
      wf[cb] = *(const short8v*)(wfb + (ln15 * 16 + cb) * 32 + g * 8);
    float fbias[16];
#pragma unroll
    for (int cb = 0; cb < 16; ++cb) fbias[cb] = bf[ln15 * 16 + cb];

    for (int tile = fb_ * 4 + wave; tile < E_ / 16; tile += FILM_BLKS * 4) {
      const int e0 = tile * 16;
      // A frag: row = e0+ln15, k = g*8+j (zero for k>=16)
      short8v af = {0, 0, 0, 0, 0, 0, 0, 0};
      if (g < 2) {
        const float* ap = ea + (size_t)(e0 + ln15) * 16 + g * 8;
        const float4 a0 = *(const float4*)ap;
        const float4 a1 = *(const float4*)(ap + 4);
        af[0] = bfb(a0.x); af[1] = bfb(a0.y); af[2] = bfb(a0.z); af[3] = bfb(a0.w);
        af[4] = bfb(a1.x); af[5] = bfb(a1.y); af[6] = bfb(a1.z); af[7] = bfb(a1.w);
      }

#pragma unroll
      for (int half = 0; half < 2; ++half) {
        f32x4 acc[8];
#pragma unroll
        for (int c8 = 0; c8 < 8; ++c8) {
          acc[c8] = (f32x4){0.f, 0.f, 0.f, 0.f};
          acc[c8] = __builtin_amdgcn_mfma_f32_16x16x32_bf16(af, wf[half * 8 + c8],
                                                            acc[c8], 0, 0, 0);
        }
#pragma unroll
        for (int r = 0; r < 4; ++r) {
          const int d0 = pk4fp8(acc[0][r] + fbias[half * 8 + 0],
                                acc[1][r] + fbias[half * 8 + 1],
                                acc[2][r] + fbias[half * 8 + 2],
                                acc[3][r] + fbias[half * 8 + 3]);
          const int d1 = pk4fp8(acc[4][r] + fbias[half * 8 + 4],
                                acc[5][r] + fbias[half * 8 + 5],
                                acc[6][r] + fbias[half * 8 + 6],
                                acc[7][r] + fbias[half * 8 + 7]);
          uint2 st; st.x = (unsigned)d0; st.y = (unsigned)d1;
          *(uint2*)(film8 + (size_t)(e0 + 4 * g + r) * 256 + ln15 * 16 + half * 8) = st;
        }
      }
    }
  } else {
    // ---------------- dst histogram ----------------
    const int e = (blk - QKV_BLKS - FILM_BLKS) * 256 + threadIdx.x;
    if (e < E_) atomicAdd(&cnt[ei[E_ + e]], 1);
  }
}

// ---------------------------------------------------------------------------
// CSR scan
// ---------------------------------------------------------------------------
__global__ __launch_bounds__(1024) void csr_scan(const int* __restrict__ cnt,
                                                 int* __restrict__ rowptr,
                                                 int* __restrict__ fill) {
  __shared__ int part[1024];
  const int t = threadIdx.x;
  int local[10];
  int sum = 0;
#pragma unroll
  for (int i = 0; i < 10; ++i) {
    const int idx = t * 10 + i;
    local[i] = sum;
    sum += (idx < N_) ? cnt[idx] : 0;
  }
  part[t] = sum;
  __syncthreads();
  for (int off = 1; off < 1024; off <<= 1) {
    const int v = (t >= off) ? part[t - off] : 0;
    __syncthreads();
    part[t] += v;
    __syncthreads();
  }
  const int excl = (t == 0) ? 0 : part[t - 1];
#pragma unroll
  for (int i = 0; i < 10; ++i) {
    const int idx = t * 10 + i;
    if (idx <= N_) {
      const int o = excl + local[i];
      rowptr[idx] = o;
      if (idx < N_) fill[idx] = o;
    }
  }
}

// scatter: CSR-ordered src + original-edge-id map
__global__ __launch_bounds__(256) void csr_scatter(
    const int* __restrict__ ei, int* __restrict__ fill,
    int* __restrict__ esrc, int* __restrict__ eord) {
  const int e = blockIdx.x * 256 + threadIdx.x;
  if (e < E_) {
    const int dst = ei[E_ + e];
    const int pos = atomicAdd(&fill[dst], 1);
    esrc[pos] = ei[e];
    eord[pos] = e;
  }
}

// ---------------------------------------------------------------------------
// K2: fused logits + softmax + aggregation — ZERO shuffles in the edge loop.
// Persistent: PGRID blocks x 4 waves; wave = node (grid-stride).
// lane = e2*32 + dh*16 + b*4 + h.  film gathered via eord (original edge id).
// ---------------------------------------------------------------------------
__global__ __launch_bounds__(256) void fused_attn(
    const int* __restrict__ rowptr, const int* __restrict__ esrc,
    const int* __restrict__ eord, const unsigned char* __restrict__ film8,
    const unsigned short* __restrict__ Qb,
    const unsigned char* __restrict__ kv8, float* __restrict__ agg) {
  const int wave = threadIdx.x >> 6;
  const int lane = threadIdx.x & 63;
  const int e2 = lane >> 5;
  const int dh = (lane >> 4) & 1;
  const int b  = (lane >> 2) & 3;
  const int h  = lane & 3;
  const int col0 = h * 32 + dh * 16;

  for (int node = blockIdx.x * 4 + wave; node < N_; node += PGRID * 4) {
    const int beg = rowptr[node], end = rowptr[node + 1];

    float q[16];
    {
      const unsigned short* qp = Qb + ((size_t)b * N_ + node) * 128 + col0;
      const short8v t0 = *(const short8v*)qp;
      const short8v t1 = *(const short8v*)(qp + 8);
#pragma unroll
      for (int j = 0; j < 8; ++j) {
        q[j]     = b2f((unsigned short)t0[j]);
        q[8 + j] = b2f((unsigned short)t1[j]);
      }
    }
    float acc[16];
#pragma unroll
    for (int d = 0; d < 16; ++d) acc[d] = 0.f;
    float se = 0.f;

    for (int i0 = beg; i0 < end; i0 += 2) {
      const int ii = i0 + e2;
      const bool valid = ii < end;
      const int ic = valid ? ii : i0;
      const int src = esrc[ic];
      const int de  = eord[ic];
      const unsigned char* kp = kv8 + ((((size_t)src << 2) + b) << 8) + col0;
      const unsigned char* fp = film8 + (size_t)de * 256 + col0;
      const uint4 kw = *(const uint4*)kp;
      const uint4 vw = *(const uint4*)(kp + 128);
      const uint4 gw = *(const uint4*)fp;
      const uint4 tw = *(const uint4*)(fp + 128);
      const unsigned ks[4] = {kw.x, kw.y, kw.z, kw.w};
      const unsigned vs[4] = {vw.x, vw.y, vw.z, vw.w};
      const unsigned gs[4] = {gw.x, gw.y, gw.z, gw.w};
      const unsigned ts[4] = {tw.x, tw.y, tw.z, tw.w};

      float pacc[4] = {0.f, 0.f, 0.f, 0.f};
#pragma unroll
      for (int w = 0; w < 4; ++w) {
        const f32x2 k0 = fp8lo(ks[w]), k1 = fp8hi(ks[w]);
        const f32x2 g0 = fp8lo(gs[w]), g1 = fp8hi(gs[w]);
        const f32x2 t0 = fp8lo(ts[w]), t1 = fp8hi(ts[w]);
        float km;
        km = k0.x + fmaf(k0.x, g0.x, t0.x); pacc[w] = fmaf(q[4*w+0], km, pacc[w]);
        km = k0.y + fmaf(k0.y, g0.y, t0.y); pacc[w] = fmaf(q[4*w+1], km, pacc[w]);
        km = k1.x + fmaf(k1.x, g1.x, t1.x); pacc[w] = fmaf(q[4*w+2], km, pacc[w]);
        km = k1.y + fmaf(k1.y, g1.y, t1.y); pacc[w] = fmaf(q[4*w+3], km, pacc[w]);
      }
      float pl = (pacc[0] + pacc[1]) + (pacc[2] + pacc[3]);
      pl += __shfl_xor(pl, 16);   // join dh halves -> full 32-dim logit

      float ex = __expf(pl * 0.17677669529663687f);  // 1/sqrt(32)
      ex = valid ? ex : 0.f;
      se += ex;
#pragma unroll
      for (int w = 0; w < 4; ++w) {
        const f32x2 v0 = fp8lo(vs[w]), v1 = fp8hi(vs[w]);
        acc[4*w+0] = fmaf(ex, v0.x, acc[4*w+0]);
        acc[4*w+1] = fmaf(ex, v0.y, acc[4*w+1]);
        acc[4*w+2] = fmaf(ex, v1.x, acc[4*w+2]);
        acc[4*w+3] = fmaf(ex, v1.y, acc[4*w+3]);
      }
    }

    // join the two e2 slots
#pragma unroll
    for (int d = 0; d < 16; ++d) acc[d] += __shfl_xor(acc[d], 32);
    se += __shfl_xor(se, 32);

    if (e2 == 0) {
      const float inv = (end > beg) ? 1.f / se : 0.f;
      float* ap = agg + ((size_t)b * N_ + node) * 128 + col0;
#pragma unroll
      for (int c = 0; c < 4; ++c) {
        float4 o;
        o.x = acc[c*4+0] * inv; o.y = acc[c*4+1] * inv;
        o.z = acc[c*4+2] * inv; o.w = acc[c*4+3] * inv;
        *(float4*)(ap + c * 4) = o;
      }
    }
  }
}

// ---------------------------------------------------------------------------
// K4: y = agg @ Wo + bo (MFMA); h = x + y; LayerNorm(h) -> out
// ONE WAVE per block, 16 rows/block, grid 2500.
// ---------------------------------------------------------------------------
__global__ __launch_bounds__(64) void out_ln_mfma(
    const float* __restrict__ agg, const short* __restrict__ wto,
    const float* __restrict__ bo, const float* __restrict__ x,
    const float* __restrict__ lng, const float* __restrict__ lnb,
    float* __restrict__ out) {
  __shared__ short as_[16][136];
  const int lane = threadIdx.x;
  const int ln15 = lane & 15;
  const int g    = lane >> 4;
  const long rowBase = (long)blockIdx.x * 16;

  for (int i = lane; i < 16 * 32; i += 64) {
    const int r  = i >> 5;
    const int c4 = (i & 31) * 4;
    const float4 v = *(const float4*)(agg + (rowBase + r) * 128 + c4);
    short4v sv; sv.x = bfb(v.x); sv.y = bfb(v.y); sv.z = bfb(v.z); sv.w = bfb(v.w);
    *(short4v*)&as_[r][c4] = sv;
  }
  __syncthreads();

  short8v af[4];
#pragma unroll
  for (int kk = 0; kk < 4; ++kk)
    af[kk] = *(const short8v*)&as_[ln15][kk * 32 + g * 8];

  f32x4 acc[8];
#pragma unroll
  for (int cb = 0; cb < 8; ++cb) acc[cb] = (f32x4){0.f, 0.f, 0.f, 0.f};

#pragma unroll
  for (int kk = 0; kk < 4; ++kk) {
#pragma unroll
    for (int cb = 0; cb < 8; ++cb) {
      const short8v bfr =
          *(const short8v*)(wto + (cb * 16 + ln15) * 128 + kk * 32 + g * 8);
      acc[cb] = __builtin_amdgcn_mfma_f32_16x16x32_bf16(af[kk], bfr, acc[cb], 0, 0, 0);
    }
  }

#pragma unroll
  for (int cb = 0; cb < 8; ++cb) {
    const int col = cb * 16 + ln15;
    const float bov = bo[col];
#pragma unroll
    for (int r = 0; r < 4; ++r) {
      const long row = rowBase + g * 4 + r;
      acc[cb][r] += bov + x[row * 128 + col];
    }
  }

  float s1[4], s2[4];
#pragma unroll
  for (int r = 0; r < 4; ++r) {
    s1[r] = 0.f; s2[r] = 0.f;
#pragma unroll
    for (int cb = 0; cb < 8; ++cb) {
      s1[r] += acc[cb][r];
      s2[r] = fmaf(acc[cb][r], acc[cb][r], s2[r]);
    }
  }
#pragma unroll
  for (int m = 1; m < 16; m <<= 1) {
#pragma unroll
    for (int r = 0; r < 4; ++r) {
      s1[r] += __shfl_xor(s1[r], m);
      s2[r] += __shfl_xor(s2[r], m);
    }
  }
  float mu[4], inv[4];
#pragma unroll
  for (int r = 0; r < 4; ++r) {
    mu[r] = s1[r] * (1.f / 128.f);
    const float var = s2[r] * (1.f / 128.f) - mu[r] * mu[r];
    inv[r] = rsqrtf(var + 1e-5f);
  }

#pragma unroll
  for (int cb = 0; cb < 8; ++cb) {
    const int col = cb * 16 + ln15;
    const float gv = lng[col], bv_ = lnb[col];
#pragma unroll
    for (int r = 0; r < 4; ++r) {
      const long row = rowBase + g * 4 + r;
      out[row * 128 + col] = (acc[cb][r] - mu[r]) * inv[r] * gv + bv_;
    }
  }
}

// ---------------------------------------------------------------------------
extern "C" void kernel_launch(void* const* d_in, const int* in_sizes, int n_in,
                              void* d_out, int out_size, void* d_ws, size_t ws_size,
                              hipStream_t stream) {
  const float* x   = (const float*)d_in[0];
  const int*   ei  = (const int*)d_in[1];
  const float* ea  = (const float*)d_in[2];
  const float* Wq  = (const float*)d_in[3];
  const float* bq  = (const float*)d_in[4];
  const float* Wk  = (const float*)d_in[5];
  const float* bk  = (const float*)d_in[6];
  const float* Wv  = (const float*)d_in[7];
  const float* bv  = (const float*)d_in[8];
  const float* Wf  = (const float*)d_in[9];
  const float* bf  = (const float*)d_in[10];
  const float* Wo  = (const float*)d_in[11];
  const float* bo  = (const float*)d_in[12];
  const float* lng = (const float*)d_in[13];
  const float* lnb = (const float*)d_in[14];
  float* out = (float*)d_out;

  const size_t NQ = (size_t)B_ * N_ * HID_;  // 5,120,000

  char* base = (char*)d_ws;
  size_t off = 0;
  unsigned short* Qb = (unsigned short*)(base + off); off += NQ * 2;   // 10.24MB
  float* agg  = (float*)(base + off); off += NQ * 4;                   // 20.48MB
  unsigned char* kv8 = (unsigned char*)(base + off);
  off += (size_t)B_ * N_ * 256;                                        // 10.24MB
  unsigned char* film8 = (unsigned char*)(base + off);
  off += (size_t)E_ * 256;                                             // 40.96MB
  short* wt   = (short*)(base + off); off += 4 * 16384 * 2;            // 128KB
  short* wfb  = (short*)(base + off); off += 256 * 32 * 2;             // 16KB
  int*  cnt    = (int*)(base + off); off += N_ * 4;
  int*  rowptr = (int*)(base + off); off += (N_ + 1) * 4;
  int*  fill   = (int*)(base + off); off += N_ * 4;
  int*  esrc   = (int*)(base + off); off += E_ * 4;
  int*  eord   = (int*)(base + off); off += E_ * 4;

  hipMemsetAsync(cnt, 0, N_ * sizeof(int), stream);

  wt_prep<<<288, 256, 0, stream>>>(Wq, Wk, Wv, Wo, Wf, wt, wfb);
  phase1<<<QKV_BLKS + FILM_BLKS + HIST_BLKS, 256, 0, stream>>>(
      x, wt, bq, bk, bv, Qb, kv8, ea, wfb, bf, film8, ei, cnt);
  csr_scan<<<1, 1024, 0, stream>>>(cnt, rowptr, fill);
  csr_scatter<<<(E_ + 255) / 256, 256, 0, stream>>>(ei, fill, esrc, eord);
  fused_attn<<<PGRID, 256, 0, stream>>>(rowptr, esrc, eord, film8, Qb, kv8, agg);
  out_ln_mfma<<<(B_ * N_) / 16, 64, 0, stream>>>(agg, wt + 3 * 16384, bo, x, lng, lnb, out);
}